// Round 4
// baseline (557.758 us; speedup 1.0000x reference)
//
#include <hip/hip_runtime.h>
#include <math.h>

// ---------------------------------------------------------------------------
// GCN diffusion forward on MI355X — round 4.
// vs R3: GEMM rebuilt. X staged TRANSPOSED in LDS (xl[k][row], quad-XOR
// swizzle, 16B aligned) so each thread's 4 rows at step k are ONE
// ds_read_b128. W read directly from global (wave-broadcast -> L1), no W
// LDS. LDS/block 16-32KB -> ~6 blocks/CU. Thread = 4 rows x 8 cols.
// ---------------------------------------------------------------------------

__global__ __launch_bounds__(256) void zero_kernel(int* __restrict__ deg,
                                                   int* __restrict__ flag, int n) {
    int i = blockIdx.x * 256 + threadIdx.x;
    if (i < n) { deg[i] = 0; flag[i] = 0; }
}

__global__ __launch_bounds__(256) void count_deg_kernel(const int* __restrict__ ei,
                                                        int* __restrict__ deg, int e) {
    int i = blockIdx.x * 256 + threadIdx.x;
    if (i < e) atomicAdd(&deg[ei[e + i]], 1);   // dst row of edge_index
}

__global__ __launch_bounds__(256) void flags_kernel(const int* __restrict__ anm, int na,
                                                    const int* __restrict__ nrm, int nn,
                                                    int* __restrict__ flag) {
    int i = blockIdx.x * 256 + threadIdx.x;
    if (i < na) atomicMax(&flag[anm[i]], 1);
    if (i < nn) atomicMax(&flag[nrm[i]], 2);    // norm (2) overrides anm (1)
}

__global__ __launch_bounds__(256) void dinv_kernel(const int* __restrict__ deg,
                                                   float* __restrict__ dinv, int n) {
    int i = blockIdx.x * 256 + threadIdx.x;
    if (i < n) dinv[i] = rsqrtf((float)deg[i] + 1.0f);
}

// ---- exclusive scan of deg into rowstart (3-kernel, 1024 elems/block) ----
__global__ __launch_bounds__(256) void scan1_kernel(const int* __restrict__ deg,
                                                    int* __restrict__ rowstart,
                                                    int* __restrict__ blocksum, int n) {
    __shared__ int ts[256];
    int t = threadIdx.x;
    int base = blockIdx.x * 1024 + t * 4;
    int v0 = 0, v1 = 0, v2 = 0, v3 = 0;
    if (base + 0 < n) v0 = deg[base + 0];
    if (base + 1 < n) v1 = deg[base + 1];
    if (base + 2 < n) v2 = deg[base + 2];
    if (base + 3 < n) v3 = deg[base + 3];
    int s = v0 + v1 + v2 + v3;
    ts[t] = s;
    __syncthreads();
    for (int off = 1; off < 256; off <<= 1) {
        int add = (t >= off) ? ts[t - off] : 0;
        __syncthreads();
        ts[t] += add;
        __syncthreads();
    }
    if (t == 255) blocksum[blockIdx.x] = ts[255];
    int excl = ts[t] - s;
    if (base + 0 < n) rowstart[base + 0] = excl; excl += v0;
    if (base + 1 < n) rowstart[base + 1] = excl; excl += v1;
    if (base + 2 < n) rowstart[base + 2] = excl; excl += v2;
    if (base + 3 < n) rowstart[base + 3] = excl;
}

__global__ void scan2_kernel(int* __restrict__ blocksum, int nb) {
    if (threadIdx.x == 0 && blockIdx.x == 0) {
        int run = 0;
        for (int i = 0; i < nb; ++i) { int v = blocksum[i]; blocksum[i] = run; run += v; }
    }
}

__global__ __launch_bounds__(256) void scan3_kernel(int* __restrict__ rowstart,
                                                    const int* __restrict__ blocksum,
                                                    int* __restrict__ writepos, int n, int e) {
    int i = blockIdx.x * 256 + threadIdx.x;
    if (i < n) {
        int v = rowstart[i] + blocksum[i >> 10];
        rowstart[i] = v;
        writepos[i] = v;
    }
    if (i == 0) rowstart[n] = e;
}

// CSR fill: one 8B scattered write per edge: (src, bits(dinv[src]))
__global__ __launch_bounds__(256) void fill_csr_kernel(const int* __restrict__ ei,
                                                       int* __restrict__ writepos,
                                                       int2* __restrict__ cs,
                                                       const float* __restrict__ dinv, int e) {
    int i = blockIdx.x * 256 + threadIdx.x;
    if (i >= e) return;
    int src = ei[i];
    int dst = ei[e + i];
    int p = atomicAdd(&writepos[dst], 1);
    cs[p] = make_int2(src, __float_as_int(dinv[src]));
}

// ---- time embedding MLP: [1,64] through two 64x64 layers with SiLU ----
__global__ void temb_kernel(const int* __restrict__ t,
                            const float* __restrict__ w1, const float* __restrict__ b1,
                            const float* __restrict__ w2, const float* __restrict__ b2,
                            float* __restrict__ temb) {
    __shared__ float emb[64], hid[64];
    int j = threadIdx.x;  // 64 threads
    float tf = (float)t[0];
    int h = j & 31;
    float freq = expf((float)h * -0.29710775393976190f);  // -ln(10000)/31
    float arg = tf * freq;
    emb[j] = (j < 32) ? sinf(arg) : cosf(arg);
    __syncthreads();
    float a = b1[j];
    for (int k = 0; k < 64; ++k) a = fmaf(emb[k], w1[k * 64 + j], a);
    hid[j] = a / (1.0f + expf(-a));  // SiLU
    __syncthreads();
    float o = b2[j];
    for (int k = 0; k < 64; ++k) o = fmaf(hid[k], w2[k * 64 + j], o);
    temb[j] = o;
}

// ---- x_t = noise_x + temb + label_emb[flag], float4 vectorized ----
__global__ __launch_bounds__(256) void xt_kernel(const float* __restrict__ nx,
                                                 const float* __restrict__ temb,
                                                 const float* __restrict__ lemb,
                                                 const int* __restrict__ flag,
                                                 float* __restrict__ xt, int n) {
    int t = blockIdx.x * 256 + threadIdx.x;
    int total = n * 16;
    if (t >= total) return;
    int row = t >> 4;
    int c4 = (t & 15) * 4;
    float4 v = *(const float4*)(nx + (size_t)row * 64 + c4);
    float4 tv = *(const float4*)(temb + c4);
    v.x += tv.x; v.y += tv.y; v.z += tv.z; v.w += tv.w;
    int f = flag[row];
    if (f) {
        const float* le = lemb + (f == 1 ? 64 : 0);  // 1->label_emb[1], 2->label_emb[0]
        float4 lv = *(const float4*)(le + c4);
        v.x += lv.x; v.y += lv.y; v.z += lv.z; v.w += lv.w;
    }
    *(float4*)(xt + (size_t)row * 64 + c4) = v;
}

// ---- aggregation over 64-dim rows: one wave per node, unroll x8 ----
template <bool BIAS_SILU>
__global__ __launch_bounds__(256) void agg64_kernel(const float* __restrict__ xw,
                                                    const int* __restrict__ rowstart,
                                                    const int2* __restrict__ cs,
                                                    const float* __restrict__ dinv,
                                                    const float* __restrict__ bias,
                                                    float* __restrict__ y, int n) {
    int wid = (int)(((size_t)blockIdx.x * 256 + threadIdx.x) >> 6);
    int lane = threadIdx.x & 63;
    if (wid >= n) return;
    float di = dinv[wid];
    int s = rowstart[wid], e1 = rowstart[wid + 1];
    float a0 = 0.f, a1 = 0.f, a2 = 0.f, a3 = 0.f;
    float a4 = 0.f, a5 = 0.f, a6 = 0.f, a7 = 0.f;
    int e = s;
    for (; e + 8 <= e1; e += 8) {
        int2 c0 = cs[e], c1 = cs[e + 1], c2 = cs[e + 2], c3 = cs[e + 3];
        int2 c4 = cs[e + 4], c5 = cs[e + 5], c6 = cs[e + 6], c7 = cs[e + 7];
        float v0 = xw[(size_t)c0.x * 64 + lane];
        float v1 = xw[(size_t)c1.x * 64 + lane];
        float v2 = xw[(size_t)c2.x * 64 + lane];
        float v3 = xw[(size_t)c3.x * 64 + lane];
        float v4 = xw[(size_t)c4.x * 64 + lane];
        float v5 = xw[(size_t)c5.x * 64 + lane];
        float v6 = xw[(size_t)c6.x * 64 + lane];
        float v7 = xw[(size_t)c7.x * 64 + lane];
        a0 = fmaf(v0, __int_as_float(c0.y) * di, a0);
        a1 = fmaf(v1, __int_as_float(c1.y) * di, a1);
        a2 = fmaf(v2, __int_as_float(c2.y) * di, a2);
        a3 = fmaf(v3, __int_as_float(c3.y) * di, a3);
        a4 = fmaf(v4, __int_as_float(c4.y) * di, a4);
        a5 = fmaf(v5, __int_as_float(c5.y) * di, a5);
        a6 = fmaf(v6, __int_as_float(c6.y) * di, a6);
        a7 = fmaf(v7, __int_as_float(c7.y) * di, a7);
    }
    for (; e + 4 <= e1; e += 4) {
        int2 c0 = cs[e], c1 = cs[e + 1], c2 = cs[e + 2], c3 = cs[e + 3];
        float v0 = xw[(size_t)c0.x * 64 + lane];
        float v1 = xw[(size_t)c1.x * 64 + lane];
        float v2 = xw[(size_t)c2.x * 64 + lane];
        float v3 = xw[(size_t)c3.x * 64 + lane];
        a0 = fmaf(v0, __int_as_float(c0.y) * di, a0);
        a1 = fmaf(v1, __int_as_float(c1.y) * di, a1);
        a2 = fmaf(v2, __int_as_float(c2.y) * di, a2);
        a3 = fmaf(v3, __int_as_float(c3.y) * di, a3);
    }
    for (; e < e1; ++e) {
        int2 c = cs[e];
        a0 = fmaf(xw[(size_t)c.x * 64 + lane], __int_as_float(c.y) * di, a0);
    }
    float acc = ((a0 + a1) + (a2 + a3)) + ((a4 + a5) + (a6 + a7));
    acc = fmaf(xw[(size_t)wid * 64 + lane], di * di, acc);
    if (BIAS_SILU) {
        acc += bias[lane];
        acc = acc / (1.0f + expf(-acc));
    }
    y[(size_t)wid * 64 + lane] = acc;
}

// ---------------------------------------------------------------------------
// GEMM v2: y[n][M] = sum over NQ 64-wide k-quarters of xq @ wq (+bias,silu).
// Tile: ROWS rows (64 for M=128, 128 for M=64) x M cols per 256-thread block.
// X quarter staged TRANSPOSED: xl[k][ROWS], quad-XOR swizzled (16B aligned).
// Per k: one ds_read_b128 = thread's 4 rows; W read from global (broadcast,
// L1-resident). Thread = 4 rows x 8 cols -> 32 FMA per k.
// NQ==1: x stride 64. NQ==2: stride 128, quarters k=0,64. NQ==4: xa,xb
// stride 128 (concat). W is [NQ*64][M] row-major. MODE 1 = +bias+SiLU.
// ---------------------------------------------------------------------------
template <int M, int NQ, int MODE>
__global__ __launch_bounds__(256, 4) void gemm2_kernel(const float* __restrict__ xa,
                                                       const float* __restrict__ xb,
                                                       const float* __restrict__ w,
                                                       const float* __restrict__ bias,
                                                       float* __restrict__ y, int n) {
    constexpr int ROWS = (M == 128) ? 64 : 128;
    constexpr int RGS = ROWS / 4;          // row groups (quads): 16 or 32
    constexpr int QMASK = RGS - 1;
    constexpr int XSTRIDE = (NQ == 1) ? 64 : 128;
    constexpr int F4PT = ROWS / 16;        // staging float4s per thread: 4 or 8
    __shared__ float xl[64 * ROWS];

    const int t = threadIdx.x;
    const int rg = t & (RGS - 1);
    const int cg = t / RGS;                // 16 (M=128) or 8 (M=64) col groups
    const int row0 = blockIdx.x * ROWS;

    float acc[4][8];
#pragma unroll
    for (int i = 0; i < 4; ++i)
#pragma unroll
        for (int j = 0; j < 8; ++j) acc[i][j] = 0.f;

#pragma unroll
    for (int q = 0; q < NQ; ++q) {
        const float* xs = (NQ == 4 && q >= 2) ? xb : xa;
        const int koff = (NQ == 1) ? 0 : (q & 1) * 64;
        if (q) __syncthreads();
        // stage X quarter transposed+swizzled: ROWS x 64 floats
#pragma unroll
        for (int i = 0; i < F4PT; ++i) {
            int fid = i * 256 + t;
            int r = fid >> 4;              // 0..ROWS-1
            int c4 = (fid & 15) * 4;       // k base
            int gr = row0 + r;
            float4 v = make_float4(0.f, 0.f, 0.f, 0.f);
            if (gr < n) v = *(const float4*)(xs + (size_t)gr * XSTRIDE + koff + c4);
            int rq = r >> 2, rm = r & 3;
#pragma unroll
            for (int j = 0; j < 4; ++j) {
                int k = c4 + j;
                int qs = (rq ^ (k >> 2)) & QMASK;
                xl[k * ROWS + qs * 4 + rm] = (&v.x)[j];
            }
        }
        __syncthreads();
        const float* wq = w + (size_t)q * 64 * M + cg * 8;
#pragma unroll 4
        for (int k = 0; k < 64; ++k) {
            int qs = (rg ^ (k >> 2)) & QMASK;
            float4 xv = *(const float4*)(&xl[k * ROWS + qs * 4]);
            float4 wv0 = *(const float4*)(wq + k * M);
            float4 wv1 = *(const float4*)(wq + k * M + 4);
            const float* xvp = &xv.x;
            const float* wp0 = &wv0.x;
            const float* wp1 = &wv1.x;
#pragma unroll
            for (int i = 0; i < 4; ++i) {
                float xi = xvp[i];
#pragma unroll
                for (int j = 0; j < 4; ++j) {
                    acc[i][j] = fmaf(xi, wp0[j], acc[i][j]);
                    acc[i][4 + j] = fmaf(xi, wp1[j], acc[i][4 + j]);
                }
            }
        }
    }

    float bb[8];
    if (MODE == 1) {
#pragma unroll
        for (int j = 0; j < 8; ++j) bb[j] = bias[cg * 8 + j];
    }
#pragma unroll
    for (int i = 0; i < 4; ++i) {
        int row = row0 + rg * 4 + i;
        if (row >= n) break;
        float* yr = y + (size_t)row * M + cg * 8;
        float o[8];
#pragma unroll
        for (int j = 0; j < 8; ++j) {
            float v = acc[i][j];
            if (MODE == 1) { v += bb[j]; v = v / (1.0f + expf(-v)); }
            o[j] = v;
        }
        *(float4*)(yr) = make_float4(o[0], o[1], o[2], o[3]);
        *(float4*)(yr + 4) = make_float4(o[4], o[5], o[6], o[7]);
    }
}

extern "C" void kernel_launch(void* const* d_in, const int* in_sizes, int n_in,
                              void* d_out, int out_size, void* d_ws, size_t ws_size,
                              hipStream_t stream) {
    const float* noise_x = (const float*)d_in[0];
    const int*   edge    = (const int*)d_in[1];
    const int*   tptr    = (const int*)d_in[2];
    const int*   anm     = (const int*)d_in[3];
    const int*   nrm     = (const int*)d_in[4];
    const float* tw1     = (const float*)d_in[5];
    const float* tb1     = (const float*)d_in[6];
    const float* tw2     = (const float*)d_in[7];
    const float* tb2     = (const float*)d_in[8];
    const float* lemb    = (const float*)d_in[9];
    const float* w0      = (const float*)d_in[10];
    const float* b0      = (const float*)d_in[11];
    const float* w1      = (const float*)d_in[12];
    const float* b1      = (const float*)d_in[13];
    const float* w2      = (const float*)d_in[14];
    const float* b2      = (const float*)d_in[15];
    const float* w3      = (const float*)d_in[16];
    const float* b3      = (const float*)d_in[17];

    const int N = in_sizes[0] / 64;
    const int E = in_sizes[1] / 2;
    const int na = in_sizes[3];
    const int nn = in_sizes[4];
    float* out = (float*)d_out;

    // workspace carve-out (256B aligned)
    char* ws = (char*)d_ws;
    size_t o = 0;
    auto carve = [&](size_t bytes) -> char* {
        char* p = ws + o;
        o += (bytes + 255) & ~(size_t)255;
        return p;
    };
    int*   deg      = (int*)carve((size_t)N * 4);
    int*   flag     = (int*)carve((size_t)N * 4);
    int*   rowstart = (int*)carve((size_t)(N + 1) * 4);
    int*   writepos = (int*)carve((size_t)N * 4);
    int*   blocksum = (int*)carve(4096);
    int2*  cs       = (int2*)carve((size_t)E * 8);
    float* dinv     = (float*)carve((size_t)N * 4);
    float* temb     = (float*)carve(256);
    float* bufP     = (float*)carve((size_t)N * 64 * 4);   // x_t -> xw1 -> aggH1 -> z3
    float* bufQ     = (float*)carve((size_t)N * 64 * 4);   // aggX -> h1
    float* bufR     = (float*)carve((size_t)N * 128 * 4);  // h0 (live to end)
    float* bufS     = (float*)carve((size_t)N * 128 * 4);  // h2

    const int nblkN = (N + 255) / 256;
    const int nblkE = (E + 255) / 256;
    const int nb = (N + 1023) / 1024;
    const int nmax = na > nn ? na : nn;
    const int aggBlk = (N + 3) / 4;          // 4 waves (nodes) per 256-thread block
    const int g64  = (N + 63) / 64;          // 64-row tiles  (M=128 gemms)
    const int g128 = (N + 127) / 128;        // 128-row tiles (M=64 gemms)

    zero_kernel<<<nblkN, 256, 0, stream>>>(deg, flag, N);
    count_deg_kernel<<<nblkE, 256, 0, stream>>>(edge, deg, E);
    flags_kernel<<<(nmax + 255) / 256, 256, 0, stream>>>(anm, na, nrm, nn, flag);
    dinv_kernel<<<nblkN, 256, 0, stream>>>(deg, dinv, N);
    scan1_kernel<<<nb, 256, 0, stream>>>(deg, rowstart, blocksum, N);
    scan2_kernel<<<1, 64, 0, stream>>>(blocksum, nb);
    scan3_kernel<<<nblkN, 256, 0, stream>>>(rowstart, blocksum, writepos, N, E);
    fill_csr_kernel<<<nblkE, 256, 0, stream>>>(edge, writepos, cs, dinv, E);
    temb_kernel<<<1, 64, 0, stream>>>(tptr, tw1, tb1, tw2, tb2, temb);
    xt_kernel<<<((size_t)N * 16 + 255) / 256, 256, 0, stream>>>(noise_x, temb, lemb, flag, bufP, N);

    // conv0: aggX = agg(x_t); h0 = silu(aggX @ w0 + b0)
    agg64_kernel<false><<<aggBlk, 256, 0, stream>>>(bufP, rowstart, cs, dinv, nullptr, bufQ, N);
    gemm2_kernel<128, 1, 1><<<g64, 256, 0, stream>>>(bufQ, nullptr, w0, b0, bufR, N);
    // conv1: xw1 = h0 @ w1; h1 = silu(agg(xw1) + b1)
    gemm2_kernel<64, 2, 0><<<g128, 256, 0, stream>>>(bufR, nullptr, w1, nullptr, bufP, N);
    agg64_kernel<true><<<aggBlk, 256, 0, stream>>>(bufP, rowstart, cs, dinv, b1, bufQ, N);
    // conv2: aggH1 = agg(h1); h2 = silu(aggH1 @ w2 + b2)
    agg64_kernel<false><<<aggBlk, 256, 0, stream>>>(bufQ, rowstart, cs, dinv, nullptr, bufP, N);
    gemm2_kernel<128, 1, 1><<<g64, 256, 0, stream>>>(bufP, nullptr, w2, b2, bufS, N);
    // conv3: z3 = h2 @ w3[0:128] + h0 @ w3[128:256]; out = silu(agg(z3) + b3)
    gemm2_kernel<64, 4, 0><<<g128, 256, 0, stream>>>(bufS, bufR, w3, nullptr, bufP, N);
    agg64_kernel<true><<<aggBlk, 256, 0, stream>>>(bufP, rowstart, cs, dinv, b3, out, N);
}

// Round 5
// 416.445 us; speedup vs baseline: 1.3393x; 1.3393x over previous
//
#include <hip/hip_runtime.h>
#include <math.h>

// ---------------------------------------------------------------------------
// GCN diffusion forward on MI355X — round 5.
// vs R4: all GEMMs -> bf16 MFMA (16x16x32), no LDS, no syncthreads.
//   Activations consumed by GEMMs are stored bf16 by their producers
//   (agg0/agg2 outputs, gemm0/gemm2 outputs). Weights converted+swizzled
//   to B-fragment order once per call. Accumulation f32; bias+SiLU fused.
// Dataflow:
//   xt(f32) -> agg0 -> aggX(bf16) -> G0[64->128,+b0,silu] -> h0(bf16)
//   h0 -> G1[128->64] -> xw1(f32) -> agg1(+b1,silu) -> h1(f32)
//   h1 -> agg2 -> aggH1(bf16) -> G2[64->128,+b2,silu] -> h2(bf16)
//   (h2,h0) -> G3[cat 256->64] -> z3(f32) -> agg3(+b3,silu) -> out
// ---------------------------------------------------------------------------

typedef unsigned short ushortT;
typedef __attribute__((ext_vector_type(8))) short short8v;
typedef __attribute__((ext_vector_type(4))) float f32x4;

__device__ __forceinline__ ushortT f2bf(float f) {
    unsigned int u = __float_as_uint(f);
    u += 0x7FFFu + ((u >> 16) & 1u);     // round-to-nearest-even
    return (ushortT)(u >> 16);
}

__global__ __launch_bounds__(256) void zero_kernel(int* __restrict__ deg,
                                                   int* __restrict__ flag, int n) {
    int i = blockIdx.x * 256 + threadIdx.x;
    if (i < n) { deg[i] = 0; flag[i] = 0; }
}

__global__ __launch_bounds__(256) void count_deg_kernel(const int* __restrict__ ei,
                                                        int* __restrict__ deg, int e) {
    int i = blockIdx.x * 256 + threadIdx.x;
    if (i < e) atomicAdd(&deg[ei[e + i]], 1);   // dst row of edge_index
}

__global__ __launch_bounds__(256) void flags_kernel(const int* __restrict__ anm, int na,
                                                    const int* __restrict__ nrm, int nn,
                                                    int* __restrict__ flag) {
    int i = blockIdx.x * 256 + threadIdx.x;
    if (i < na) atomicMax(&flag[anm[i]], 1);
    if (i < nn) atomicMax(&flag[nrm[i]], 2);    // norm (2) overrides anm (1)
}

__global__ __launch_bounds__(256) void dinv_kernel(const int* __restrict__ deg,
                                                   float* __restrict__ dinv, int n) {
    int i = blockIdx.x * 256 + threadIdx.x;
    if (i < n) dinv[i] = rsqrtf((float)deg[i] + 1.0f);
}

// ---- exclusive scan of deg into rowstart (3-kernel, 1024 elems/block) ----
__global__ __launch_bounds__(256) void scan1_kernel(const int* __restrict__ deg,
                                                    int* __restrict__ rowstart,
                                                    int* __restrict__ blocksum, int n) {
    __shared__ int ts[256];
    int t = threadIdx.x;
    int base = blockIdx.x * 1024 + t * 4;
    int v0 = 0, v1 = 0, v2 = 0, v3 = 0;
    if (base + 0 < n) v0 = deg[base + 0];
    if (base + 1 < n) v1 = deg[base + 1];
    if (base + 2 < n) v2 = deg[base + 2];
    if (base + 3 < n) v3 = deg[base + 3];
    int s = v0 + v1 + v2 + v3;
    ts[t] = s;
    __syncthreads();
    for (int off = 1; off < 256; off <<= 1) {
        int add = (t >= off) ? ts[t - off] : 0;
        __syncthreads();
        ts[t] += add;
        __syncthreads();
    }
    if (t == 255) blocksum[blockIdx.x] = ts[255];
    int excl = ts[t] - s;
    if (base + 0 < n) rowstart[base + 0] = excl; excl += v0;
    if (base + 1 < n) rowstart[base + 1] = excl; excl += v1;
    if (base + 2 < n) rowstart[base + 2] = excl; excl += v2;
    if (base + 3 < n) rowstart[base + 3] = excl;
}

__global__ void scan2_kernel(int* __restrict__ blocksum, int nb) {
    if (threadIdx.x == 0 && blockIdx.x == 0) {
        int run = 0;
        for (int i = 0; i < nb; ++i) { int v = blocksum[i]; blocksum[i] = run; run += v; }
    }
}

__global__ __launch_bounds__(256) void scan3_kernel(int* __restrict__ rowstart,
                                                    const int* __restrict__ blocksum,
                                                    int* __restrict__ writepos, int n, int e) {
    int i = blockIdx.x * 256 + threadIdx.x;
    if (i < n) {
        int v = rowstart[i] + blocksum[i >> 10];
        rowstart[i] = v;
        writepos[i] = v;
    }
    if (i == 0) rowstart[n] = e;
}

// CSR fill: one 8B scattered write per edge: (src, bits(dinv[src]))
__global__ __launch_bounds__(256) void fill_csr_kernel(const int* __restrict__ ei,
                                                       int* __restrict__ writepos,
                                                       int2* __restrict__ cs,
                                                       const float* __restrict__ dinv, int e) {
    int i = blockIdx.x * 256 + threadIdx.x;
    if (i >= e) return;
    int src = ei[i];
    int dst = ei[e + i];
    int p = atomicAdd(&writepos[dst], 1);
    cs[p] = make_int2(src, __float_as_int(dinv[src]));
}

// ---- time embedding MLP: [1,64] through two 64x64 layers with SiLU ----
__global__ void temb_kernel(const int* __restrict__ t,
                            const float* __restrict__ w1, const float* __restrict__ b1,
                            const float* __restrict__ w2, const float* __restrict__ b2,
                            float* __restrict__ temb) {
    __shared__ float emb[64], hid[64];
    int j = threadIdx.x;  // 64 threads
    float tf = (float)t[0];
    int h = j & 31;
    float freq = expf((float)h * -0.29710775393976190f);  // -ln(10000)/31
    float arg = tf * freq;
    emb[j] = (j < 32) ? sinf(arg) : cosf(arg);
    __syncthreads();
    float a = b1[j];
    for (int k = 0; k < 64; ++k) a = fmaf(emb[k], w1[k * 64 + j], a);
    hid[j] = a / (1.0f + expf(-a));  // SiLU
    __syncthreads();
    float o = b2[j];
    for (int k = 0; k < 64; ++k) o = fmaf(hid[k], w2[k * 64 + j], o);
    temb[j] = o;
}

// ---- x_t = noise_x + temb + label_emb[flag], float4 vectorized ----
__global__ __launch_bounds__(256) void xt_kernel(const float* __restrict__ nx,
                                                 const float* __restrict__ temb,
                                                 const float* __restrict__ lemb,
                                                 const int* __restrict__ flag,
                                                 float* __restrict__ xt, int n) {
    int t = blockIdx.x * 256 + threadIdx.x;
    int total = n * 16;
    if (t >= total) return;
    int row = t >> 4;
    int c4 = (t & 15) * 4;
    float4 v = *(const float4*)(nx + (size_t)row * 64 + c4);
    float4 tv = *(const float4*)(temb + c4);
    v.x += tv.x; v.y += tv.y; v.z += tv.z; v.w += tv.w;
    int f = flag[row];
    if (f) {
        const float* le = lemb + (f == 1 ? 64 : 0);  // 1->label_emb[1], 2->label_emb[0]
        float4 lv = *(const float4*)(le + c4);
        v.x += lv.x; v.y += lv.y; v.z += lv.z; v.w += lv.w;
    }
    *(float4*)(xt + (size_t)row * 64 + c4) = v;
}

// ---- weight convert + swizzle to B-fragment order (all 4 gemms) ----
// Fragment layout for mfma_f32_16x16x32_bf16 B operand:
//   lane l supplies B[k][n] with n = l&15, k = kq*32 + (l>>4)*8 + j (j=0..7).
// Swizzled storage: dst[(((kq*ST + s)*64 + lane)*8 + j] so a B fragment is
// one 16B contiguous load per lane.
__global__ __launch_bounds__(256) void convw_kernel(const float* __restrict__ w0,
                                                    const float* __restrict__ w1,
                                                    const float* __restrict__ w2,
                                                    const float* __restrict__ w3,
                                                    ushortT* __restrict__ dst) {
    int i = blockIdx.x * 256 + threadIdx.x;
    if (i >= 40960) return;
    const float* src; int ST, M, base;
    if (i < 8192)       { src = w0; ST = 8; M = 128; base = 0; }
    else if (i < 16384) { src = w1; ST = 4; M = 64;  base = 8192; }
    else if (i < 24576) { src = w2; ST = 8; M = 128; base = 16384; }
    else                { src = w3; ST = 4; M = 64;  base = 24576; }
    int idx = i - base;
    int j = idx & 7;
    int lane = (idx >> 3) & 63;
    int rest = idx >> 9;
    int s = rest % ST;
    int kq = rest / ST;
    int k = kq * 32 + (lane >> 4) * 8 + j;
    int col = s * 16 + (lane & 15);
    dst[i] = f2bf(src[(size_t)k * M + col]);
}

// ---------------------------------------------------------------------------
// MFMA GEMM: Y[n][M] = A[n][K] @ W (bf16 in, f32 acc). Wave = 16 rows x M.
// Block = 4 waves = 64 rows. No LDS. A row-major bf16 (stride KA per source).
// CAT: kq >= KQT/2 switches to A2 (concat along K). Wswz pre-swizzled.
// ---------------------------------------------------------------------------
template <int KQT, int ST, bool BIAS_SILU, bool OUT_BF16, bool CAT>
__global__ __launch_bounds__(256) void mfma_gemm_kernel(const ushortT* __restrict__ A1,
                                                        const ushortT* __restrict__ A2,
                                                        const ushortT* __restrict__ Wswz,
                                                        const float* __restrict__ bias,
                                                        void* __restrict__ Yv, int n) {
    constexpr int M = ST * 16;
    constexpr int KA = (CAT ? (KQT / 2) : KQT) * 32;   // per-source row stride
    const int lane = threadIdx.x & 63;
    const int wid = threadIdx.x >> 6;
    const int row0 = blockIdx.x * 64 + wid * 16;
    const int arow = row0 + (lane & 15);
    const int kb = (lane >> 4) * 8;

    f32x4 acc[ST];
#pragma unroll
    for (int s = 0; s < ST; ++s) acc[s] = (f32x4){0.f, 0.f, 0.f, 0.f};

#pragma unroll
    for (int kq = 0; kq < KQT; ++kq) {
        const ushortT* Asrc = (CAT && kq >= KQT / 2) ? A2 : A1;
        const int kloc = (CAT && kq >= KQT / 2) ? (kq - KQT / 2) * 32 : kq * 32;
        short8v a = *(const short8v*)(Asrc + (size_t)arow * KA + kloc + kb);
        const ushortT* wp = Wswz + ((size_t)(kq * ST) * 64 + lane) * 8;
#pragma unroll
        for (int s = 0; s < ST; ++s) {
            short8v b = *(const short8v*)(wp + (size_t)s * 64 * 8);
            acc[s] = __builtin_amdgcn_mfma_f32_16x16x32_bf16(a, b, acc[s], 0, 0, 0);
        }
    }

    const int dcol = lane & 15;
    const int drow0 = row0 + (lane >> 4) * 4;
#pragma unroll
    for (int s = 0; s < ST; ++s) {
        float bv = BIAS_SILU ? bias[s * 16 + dcol] : 0.f;
#pragma unroll
        for (int r = 0; r < 4; ++r) {
            int row = drow0 + r;
            if (row >= n) continue;
            float v = acc[s][r];
            if (BIAS_SILU) { v += bv; v = v / (1.0f + expf(-v)); }
            if (OUT_BF16) ((ushortT*)Yv)[(size_t)row * M + s * 16 + dcol] = f2bf(v);
            else          ((float*)Yv)[(size_t)row * M + s * 16 + dcol] = v;
        }
    }
}

// ---- aggregation over 64-dim rows: one wave per node, unroll x8 ----
template <bool BIAS_SILU, bool OUT_BF16>
__global__ __launch_bounds__(256) void agg64_kernel(const float* __restrict__ xw,
                                                    const int* __restrict__ rowstart,
                                                    const int2* __restrict__ cs,
                                                    const float* __restrict__ dinv,
                                                    const float* __restrict__ bias,
                                                    void* __restrict__ yv, int n) {
    int wid = (int)(((size_t)blockIdx.x * 256 + threadIdx.x) >> 6);
    int lane = threadIdx.x & 63;
    if (wid >= n) return;
    float di = dinv[wid];
    int s = rowstart[wid], e1 = rowstart[wid + 1];
    float a0 = 0.f, a1 = 0.f, a2 = 0.f, a3 = 0.f;
    float a4 = 0.f, a5 = 0.f, a6 = 0.f, a7 = 0.f;
    int e = s;
    for (; e + 8 <= e1; e += 8) {
        int2 c0 = cs[e], c1 = cs[e + 1], c2 = cs[e + 2], c3 = cs[e + 3];
        int2 c4 = cs[e + 4], c5 = cs[e + 5], c6 = cs[e + 6], c7 = cs[e + 7];
        float v0 = xw[(size_t)c0.x * 64 + lane];
        float v1 = xw[(size_t)c1.x * 64 + lane];
        float v2 = xw[(size_t)c2.x * 64 + lane];
        float v3 = xw[(size_t)c3.x * 64 + lane];
        float v4 = xw[(size_t)c4.x * 64 + lane];
        float v5 = xw[(size_t)c5.x * 64 + lane];
        float v6 = xw[(size_t)c6.x * 64 + lane];
        float v7 = xw[(size_t)c7.x * 64 + lane];
        a0 = fmaf(v0, __int_as_float(c0.y) * di, a0);
        a1 = fmaf(v1, __int_as_float(c1.y) * di, a1);
        a2 = fmaf(v2, __int_as_float(c2.y) * di, a2);
        a3 = fmaf(v3, __int_as_float(c3.y) * di, a3);
        a4 = fmaf(v4, __int_as_float(c4.y) * di, a4);
        a5 = fmaf(v5, __int_as_float(c5.y) * di, a5);
        a6 = fmaf(v6, __int_as_float(c6.y) * di, a6);
        a7 = fmaf(v7, __int_as_float(c7.y) * di, a7);
    }
    for (; e + 4 <= e1; e += 4) {
        int2 c0 = cs[e], c1 = cs[e + 1], c2 = cs[e + 2], c3 = cs[e + 3];
        float v0 = xw[(size_t)c0.x * 64 + lane];
        float v1 = xw[(size_t)c1.x * 64 + lane];
        float v2 = xw[(size_t)c2.x * 64 + lane];
        float v3 = xw[(size_t)c3.x * 64 + lane];
        a0 = fmaf(v0, __int_as_float(c0.y) * di, a0);
        a1 = fmaf(v1, __int_as_float(c1.y) * di, a1);
        a2 = fmaf(v2, __int_as_float(c2.y) * di, a2);
        a3 = fmaf(v3, __int_as_float(c3.y) * di, a3);
    }
    for (; e < e1; ++e) {
        int2 c = cs[e];
        a0 = fmaf(xw[(size_t)c.x * 64 + lane], __int_as_float(c.y) * di, a0);
    }
    float acc = ((a0 + a1) + (a2 + a3)) + ((a4 + a5) + (a6 + a7));
    acc = fmaf(xw[(size_t)wid * 64 + lane], di * di, acc);
    if (BIAS_SILU) {
        acc += bias[lane];
        acc = acc / (1.0f + expf(-acc));
    }
    if (OUT_BF16) ((ushortT*)yv)[(size_t)wid * 64 + lane] = f2bf(acc);
    else          ((float*)yv)[(size_t)wid * 64 + lane] = acc;
}

extern "C" void kernel_launch(void* const* d_in, const int* in_sizes, int n_in,
                              void* d_out, int out_size, void* d_ws, size_t ws_size,
                              hipStream_t stream) {
    const float* noise_x = (const float*)d_in[0];
    const int*   edge    = (const int*)d_in[1];
    const int*   tptr    = (const int*)d_in[2];
    const int*   anm     = (const int*)d_in[3];
    const int*   nrm     = (const int*)d_in[4];
    const float* tw1     = (const float*)d_in[5];
    const float* tb1     = (const float*)d_in[6];
    const float* tw2     = (const float*)d_in[7];
    const float* tb2     = (const float*)d_in[8];
    const float* lemb    = (const float*)d_in[9];
    const float* w0      = (const float*)d_in[10];
    const float* b0      = (const float*)d_in[11];
    const float* w1      = (const float*)d_in[12];
    const float* b1      = (const float*)d_in[13];
    const float* w2      = (const float*)d_in[14];
    const float* b2      = (const float*)d_in[15];
    const float* w3      = (const float*)d_in[16];
    const float* b3      = (const float*)d_in[17];

    const int N = in_sizes[0] / 64;
    const int E = in_sizes[1] / 2;
    const int na = in_sizes[3];
    const int nn = in_sizes[4];
    float* out = (float*)d_out;

    // workspace carve-out (256B aligned)
    char* ws = (char*)d_ws;
    size_t o = 0;
    auto carve = [&](size_t bytes) -> char* {
        char* p = ws + o;
        o += (bytes + 255) & ~(size_t)255;
        return p;
    };
    int*     deg      = (int*)carve((size_t)N * 4);
    int*     flag     = (int*)carve((size_t)N * 4);
    int*     rowstart = (int*)carve((size_t)(N + 1) * 4);
    int*     writepos = (int*)carve((size_t)N * 4);
    int*     blocksum = (int*)carve(4096);
    int2*    cs       = (int2*)carve((size_t)E * 8);
    float*   dinv     = (float*)carve((size_t)N * 4);
    float*   temb     = (float*)carve(256);
    ushortT* wswz     = (ushortT*)carve(40960 * 2);
    float*   bufXT    = (float*)carve((size_t)N * 64 * 4);    // x_t, reused as h1
    ushortT* aggX     = (ushortT*)carve((size_t)N * 64 * 2);  // agg0 out (bf16)
    ushortT* h0       = (ushortT*)carve((size_t)N * 128 * 2); // G0 out (bf16)
    float*   xw1      = (float*)carve((size_t)N * 64 * 4);    // G1 out, reused as z3
    ushortT* aggH1    = (ushortT*)carve((size_t)N * 64 * 2);  // agg2 out (bf16)
    ushortT* h2       = (ushortT*)carve((size_t)N * 128 * 2); // G2 out (bf16)
    float*   h1       = bufXT;                                 // reuse
    float*   z3       = xw1;                                   // reuse

    const int nblkN = (N + 255) / 256;
    const int nblkE = (E + 255) / 256;
    const int nb = (N + 1023) / 1024;
    const int nmax = na > nn ? na : nn;
    const int aggBlk = (N + 3) / 4;          // 4 waves (nodes) per 256-thread block
    const int gblk = (N + 63) / 64;          // 64 rows per mfma-gemm block

    zero_kernel<<<nblkN, 256, 0, stream>>>(deg, flag, N);
    count_deg_kernel<<<nblkE, 256, 0, stream>>>(edge, deg, E);
    flags_kernel<<<(nmax + 255) / 256, 256, 0, stream>>>(anm, na, nrm, nn, flag);
    dinv_kernel<<<nblkN, 256, 0, stream>>>(deg, dinv, N);
    scan1_kernel<<<nb, 256, 0, stream>>>(deg, rowstart, blocksum, N);
    scan2_kernel<<<1, 64, 0, stream>>>(blocksum, nb);
    scan3_kernel<<<nblkN, 256, 0, stream>>>(rowstart, blocksum, writepos, N, E);
    fill_csr_kernel<<<nblkE, 256, 0, stream>>>(edge, writepos, cs, dinv, E);
    convw_kernel<<<160, 256, 0, stream>>>(w0, w1, w2, w3, wswz);
    temb_kernel<<<1, 64, 0, stream>>>(tptr, tw1, tb1, tw2, tb2, temb);
    xt_kernel<<<((size_t)N * 16 + 255) / 256, 256, 0, stream>>>(noise_x, temb, lemb, flag, bufXT, N);

    // conv0: aggX = agg(x_t) [bf16]; h0 = silu(aggX @ w0 + b0) [bf16]
    agg64_kernel<false, true><<<aggBlk, 256, 0, stream>>>(bufXT, rowstart, cs, dinv, nullptr, aggX, N);
    mfma_gemm_kernel<2, 8, true, true, false><<<gblk, 256, 0, stream>>>(aggX, nullptr, wswz, b0, h0, N);
    // conv1: xw1 = h0 @ w1 [f32]; h1 = silu(agg(xw1) + b1) [f32]
    mfma_gemm_kernel<4, 4, false, false, false><<<gblk, 256, 0, stream>>>(h0, nullptr, wswz + 8192, nullptr, xw1, N);
    agg64_kernel<true, false><<<aggBlk, 256, 0, stream>>>(xw1, rowstart, cs, dinv, b1, h1, N);
    // conv2: aggH1 = agg(h1) [bf16]; h2 = silu(aggH1 @ w2 + b2) [bf16]
    agg64_kernel<false, true><<<aggBlk, 256, 0, stream>>>(h1, rowstart, cs, dinv, nullptr, aggH1, N);
    mfma_gemm_kernel<2, 8, true, true, false><<<gblk, 256, 0, stream>>>(aggH1, nullptr, wswz + 16384, b2, h2, N);
    // conv3: z3 = h2 @ w3a + h0 @ w3b [f32]; out = silu(agg(z3) + b3)
    mfma_gemm_kernel<8, 4, false, false, true><<<gblk, 256, 0, stream>>>(h2, h0, wswz + 24576, nullptr, z3, N);
    agg64_kernel<true, false><<<aggBlk, 256, 0, stream>>>(z3, rowstart, cs, dinv, b3, out, N);
}

// Round 6
// 411.512 us; speedup vs baseline: 1.3554x; 1.0120x over previous
//
#include <hip/hip_runtime.h>
#include <math.h>

// ---------------------------------------------------------------------------
// GCN diffusion forward on MI355X — round 6.
// vs R5: ALL aggregation inputs are bf16 (x_t, xw1, h1, z3) — gather bytes
// halve, gathered working set 25.6->12.8MB. Producers emit bf16 directly
// (xt_kernel, G1/G3 epilogues, agg1). Accumulation stays f32.
// Dataflow:
//   xt(bf16) -> agg0 -> aggX(bf16) -> G0[64->128,+b0,silu] -> h0(bf16)
//   h0 -> G1[128->64] -> xw1(bf16) -> agg1(+b1,silu) -> h1(bf16)
//   h1 -> agg2 -> aggH1(bf16) -> G2[64->128,+b2,silu] -> h2(bf16)
//   (h2,h0) -> G3[cat 256->64] -> z3(bf16) -> agg3(+b3,silu) -> out(f32)
// ---------------------------------------------------------------------------

typedef unsigned short ushortT;
typedef __attribute__((ext_vector_type(8))) short short8v;
typedef __attribute__((ext_vector_type(4))) float f32x4;

__device__ __forceinline__ ushortT f2bf(float f) {
    unsigned int u = __float_as_uint(f);
    u += 0x7FFFu + ((u >> 16) & 1u);     // round-to-nearest-even
    return (ushortT)(u >> 16);
}
__device__ __forceinline__ float bf2f(ushortT u) {
    return __uint_as_float(((unsigned int)u) << 16);
}

__global__ __launch_bounds__(256) void zero_kernel(int* __restrict__ deg,
                                                   int* __restrict__ flag, int n) {
    int i = blockIdx.x * 256 + threadIdx.x;
    if (i < n) { deg[i] = 0; flag[i] = 0; }
}

__global__ __launch_bounds__(256) void count_deg_kernel(const int* __restrict__ ei,
                                                        int* __restrict__ deg, int e) {
    int i = blockIdx.x * 256 + threadIdx.x;
    if (i < e) atomicAdd(&deg[ei[e + i]], 1);   // dst row of edge_index
}

__global__ __launch_bounds__(256) void flags_kernel(const int* __restrict__ anm, int na,
                                                    const int* __restrict__ nrm, int nn,
                                                    int* __restrict__ flag) {
    int i = blockIdx.x * 256 + threadIdx.x;
    if (i < na) atomicMax(&flag[anm[i]], 1);
    if (i < nn) atomicMax(&flag[nrm[i]], 2);    // norm (2) overrides anm (1)
}

__global__ __launch_bounds__(256) void dinv_kernel(const int* __restrict__ deg,
                                                   float* __restrict__ dinv, int n) {
    int i = blockIdx.x * 256 + threadIdx.x;
    if (i < n) dinv[i] = rsqrtf((float)deg[i] + 1.0f);
}

// ---- exclusive scan of deg into rowstart (3-kernel, 1024 elems/block) ----
__global__ __launch_bounds__(256) void scan1_kernel(const int* __restrict__ deg,
                                                    int* __restrict__ rowstart,
                                                    int* __restrict__ blocksum, int n) {
    __shared__ int ts[256];
    int t = threadIdx.x;
    int base = blockIdx.x * 1024 + t * 4;
    int v0 = 0, v1 = 0, v2 = 0, v3 = 0;
    if (base + 0 < n) v0 = deg[base + 0];
    if (base + 1 < n) v1 = deg[base + 1];
    if (base + 2 < n) v2 = deg[base + 2];
    if (base + 3 < n) v3 = deg[base + 3];
    int s = v0 + v1 + v2 + v3;
    ts[t] = s;
    __syncthreads();
    for (int off = 1; off < 256; off <<= 1) {
        int add = (t >= off) ? ts[t - off] : 0;
        __syncthreads();
        ts[t] += add;
        __syncthreads();
    }
    if (t == 255) blocksum[blockIdx.x] = ts[255];
    int excl = ts[t] - s;
    if (base + 0 < n) rowstart[base + 0] = excl; excl += v0;
    if (base + 1 < n) rowstart[base + 1] = excl; excl += v1;
    if (base + 2 < n) rowstart[base + 2] = excl; excl += v2;
    if (base + 3 < n) rowstart[base + 3] = excl;
}

__global__ void scan2_kernel(int* __restrict__ blocksum, int nb) {
    if (threadIdx.x == 0 && blockIdx.x == 0) {
        int run = 0;
        for (int i = 0; i < nb; ++i) { int v = blocksum[i]; blocksum[i] = run; run += v; }
    }
}

__global__ __launch_bounds__(256) void scan3_kernel(int* __restrict__ rowstart,
                                                    const int* __restrict__ blocksum,
                                                    int* __restrict__ writepos, int n, int e) {
    int i = blockIdx.x * 256 + threadIdx.x;
    if (i < n) {
        int v = rowstart[i] + blocksum[i >> 10];
        rowstart[i] = v;
        writepos[i] = v;
    }
    if (i == 0) rowstart[n] = e;
}

// CSR fill: one 8B scattered write per edge: (src, bits(dinv[src]))
__global__ __launch_bounds__(256) void fill_csr_kernel(const int* __restrict__ ei,
                                                       int* __restrict__ writepos,
                                                       int2* __restrict__ cs,
                                                       const float* __restrict__ dinv, int e) {
    int i = blockIdx.x * 256 + threadIdx.x;
    if (i >= e) return;
    int src = ei[i];
    int dst = ei[e + i];
    int p = atomicAdd(&writepos[dst], 1);
    cs[p] = make_int2(src, __float_as_int(dinv[src]));
}

// ---- time embedding MLP: [1,64] through two 64x64 layers with SiLU ----
__global__ void temb_kernel(const int* __restrict__ t,
                            const float* __restrict__ w1, const float* __restrict__ b1,
                            const float* __restrict__ w2, const float* __restrict__ b2,
                            float* __restrict__ temb) {
    __shared__ float emb[64], hid[64];
    int j = threadIdx.x;  // 64 threads
    float tf = (float)t[0];
    int h = j & 31;
    float freq = expf((float)h * -0.29710775393976190f);  // -ln(10000)/31
    float arg = tf * freq;
    emb[j] = (j < 32) ? sinf(arg) : cosf(arg);
    __syncthreads();
    float a = b1[j];
    for (int k = 0; k < 64; ++k) a = fmaf(emb[k], w1[k * 64 + j], a);
    hid[j] = a / (1.0f + expf(-a));  // SiLU
    __syncthreads();
    float o = b2[j];
    for (int k = 0; k < 64; ++k) o = fmaf(hid[k], w2[k * 64 + j], o);
    temb[j] = o;
}

// ---- x_t = noise_x + temb + label_emb[flag]  -> bf16 ----
__global__ __launch_bounds__(256) void xt_kernel(const float* __restrict__ nx,
                                                 const float* __restrict__ temb,
                                                 const float* __restrict__ lemb,
                                                 const int* __restrict__ flag,
                                                 ushortT* __restrict__ xt, int n) {
    int t = blockIdx.x * 256 + threadIdx.x;
    int total = n * 16;
    if (t >= total) return;
    int row = t >> 4;
    int c4 = (t & 15) * 4;
    float4 v = *(const float4*)(nx + (size_t)row * 64 + c4);
    float4 tv = *(const float4*)(temb + c4);
    v.x += tv.x; v.y += tv.y; v.z += tv.z; v.w += tv.w;
    int f = flag[row];
    if (f) {
        const float* le = lemb + (f == 1 ? 64 : 0);  // 1->label_emb[1], 2->label_emb[0]
        float4 lv = *(const float4*)(le + c4);
        v.x += lv.x; v.y += lv.y; v.z += lv.z; v.w += lv.w;
    }
    unsigned int p0 = (unsigned int)f2bf(v.x) | ((unsigned int)f2bf(v.y) << 16);
    unsigned int p1 = (unsigned int)f2bf(v.z) | ((unsigned int)f2bf(v.w) << 16);
    *(uint2*)(xt + (size_t)row * 64 + c4) = make_uint2(p0, p1);
}

// ---- weight convert + swizzle to B-fragment order (all 4 gemms) ----
__global__ __launch_bounds__(256) void convw_kernel(const float* __restrict__ w0,
                                                    const float* __restrict__ w1,
                                                    const float* __restrict__ w2,
                                                    const float* __restrict__ w3,
                                                    ushortT* __restrict__ dst) {
    int i = blockIdx.x * 256 + threadIdx.x;
    if (i >= 40960) return;
    const float* src; int ST, M, base;
    if (i < 8192)       { src = w0; ST = 8; M = 128; base = 0; }
    else if (i < 16384) { src = w1; ST = 4; M = 64;  base = 8192; }
    else if (i < 24576) { src = w2; ST = 8; M = 128; base = 16384; }
    else                { src = w3; ST = 4; M = 64;  base = 24576; }
    int idx = i - base;
    int j = idx & 7;
    int lane = (idx >> 3) & 63;
    int rest = idx >> 9;
    int s = rest % ST;
    int kq = rest / ST;
    int k = kq * 32 + (lane >> 4) * 8 + j;
    int col = s * 16 + (lane & 15);
    dst[i] = f2bf(src[(size_t)k * M + col]);
}

// ---------------------------------------------------------------------------
// MFMA GEMM: Y[n][M] = A[n][K] @ W (bf16 in, f32 acc). Wave = 16 rows x M.
// Block = 4 waves = 64 rows. No LDS. A row-major bf16 (stride KA per source).
// CAT: kq >= KQT/2 switches to A2 (concat along K). Wswz pre-swizzled.
// ---------------------------------------------------------------------------
template <int KQT, int ST, bool BIAS_SILU, bool OUT_BF16, bool CAT>
__global__ __launch_bounds__(256) void mfma_gemm_kernel(const ushortT* __restrict__ A1,
                                                        const ushortT* __restrict__ A2,
                                                        const ushortT* __restrict__ Wswz,
                                                        const float* __restrict__ bias,
                                                        void* __restrict__ Yv, int n) {
    constexpr int M = ST * 16;
    constexpr int KA = (CAT ? (KQT / 2) : KQT) * 32;   // per-source row stride
    const int lane = threadIdx.x & 63;
    const int wid = threadIdx.x >> 6;
    const int row0 = blockIdx.x * 64 + wid * 16;
    const int arow = row0 + (lane & 15);
    const int kb = (lane >> 4) * 8;

    f32x4 acc[ST];
#pragma unroll
    for (int s = 0; s < ST; ++s) acc[s] = (f32x4){0.f, 0.f, 0.f, 0.f};

#pragma unroll
    for (int kq = 0; kq < KQT; ++kq) {
        const ushortT* Asrc = (CAT && kq >= KQT / 2) ? A2 : A1;
        const int kloc = (CAT && kq >= KQT / 2) ? (kq - KQT / 2) * 32 : kq * 32;
        short8v a = *(const short8v*)(Asrc + (size_t)arow * KA + kloc + kb);
        const ushortT* wp = Wswz + ((size_t)(kq * ST) * 64 + lane) * 8;
#pragma unroll
        for (int s = 0; s < ST; ++s) {
            short8v b = *(const short8v*)(wp + (size_t)s * 64 * 8);
            acc[s] = __builtin_amdgcn_mfma_f32_16x16x32_bf16(a, b, acc[s], 0, 0, 0);
        }
    }

    const int dcol = lane & 15;
    const int drow0 = row0 + (lane >> 4) * 4;
#pragma unroll
    for (int s = 0; s < ST; ++s) {
        float bv = BIAS_SILU ? bias[s * 16 + dcol] : 0.f;
#pragma unroll
        for (int r = 0; r < 4; ++r) {
            int row = drow0 + r;
            if (row >= n) continue;
            float v = acc[s][r];
            if (BIAS_SILU) { v += bv; v = v / (1.0f + expf(-v)); }
            if (OUT_BF16) ((ushortT*)Yv)[(size_t)row * M + s * 16 + dcol] = f2bf(v);
            else          ((float*)Yv)[(size_t)row * M + s * 16 + dcol] = v;
        }
    }
}

// ---- aggregation over 64-dim bf16 rows: one wave per node, unroll x8 ----
template <bool BIAS_SILU, bool OUT_BF16>
__global__ __launch_bounds__(256) void agg64_kernel(const ushortT* __restrict__ xw,
                                                    const int* __restrict__ rowstart,
                                                    const int2* __restrict__ cs,
                                                    const float* __restrict__ dinv,
                                                    const float* __restrict__ bias,
                                                    void* __restrict__ yv, int n) {
    int wid = (int)(((size_t)blockIdx.x * 256 + threadIdx.x) >> 6);
    int lane = threadIdx.x & 63;
    if (wid >= n) return;
    float di = dinv[wid];
    int s = rowstart[wid], e1 = rowstart[wid + 1];
    float a0 = 0.f, a1 = 0.f, a2 = 0.f, a3 = 0.f;
    float a4 = 0.f, a5 = 0.f, a6 = 0.f, a7 = 0.f;
    int e = s;
    for (; e + 8 <= e1; e += 8) {
        int2 c0 = cs[e], c1 = cs[e + 1], c2 = cs[e + 2], c3 = cs[e + 3];
        int2 c4 = cs[e + 4], c5 = cs[e + 5], c6 = cs[e + 6], c7 = cs[e + 7];
        float v0 = bf2f(xw[(size_t)c0.x * 64 + lane]);
        float v1 = bf2f(xw[(size_t)c1.x * 64 + lane]);
        float v2 = bf2f(xw[(size_t)c2.x * 64 + lane]);
        float v3 = bf2f(xw[(size_t)c3.x * 64 + lane]);
        float v4 = bf2f(xw[(size_t)c4.x * 64 + lane]);
        float v5 = bf2f(xw[(size_t)c5.x * 64 + lane]);
        float v6 = bf2f(xw[(size_t)c6.x * 64 + lane]);
        float v7 = bf2f(xw[(size_t)c7.x * 64 + lane]);
        a0 = fmaf(v0, __int_as_float(c0.y) * di, a0);
        a1 = fmaf(v1, __int_as_float(c1.y) * di, a1);
        a2 = fmaf(v2, __int_as_float(c2.y) * di, a2);
        a3 = fmaf(v3, __int_as_float(c3.y) * di, a3);
        a4 = fmaf(v4, __int_as_float(c4.y) * di, a4);
        a5 = fmaf(v5, __int_as_float(c5.y) * di, a5);
        a6 = fmaf(v6, __int_as_float(c6.y) * di, a6);
        a7 = fmaf(v7, __int_as_float(c7.y) * di, a7);
    }
    for (; e + 4 <= e1; e += 4) {
        int2 c0 = cs[e], c1 = cs[e + 1], c2 = cs[e + 2], c3 = cs[e + 3];
        float v0 = bf2f(xw[(size_t)c0.x * 64 + lane]);
        float v1 = bf2f(xw[(size_t)c1.x * 64 + lane]);
        float v2 = bf2f(xw[(size_t)c2.x * 64 + lane]);
        float v3 = bf2f(xw[(size_t)c3.x * 64 + lane]);
        a0 = fmaf(v0, __int_as_float(c0.y) * di, a0);
        a1 = fmaf(v1, __int_as_float(c1.y) * di, a1);
        a2 = fmaf(v2, __int_as_float(c2.y) * di, a2);
        a3 = fmaf(v3, __int_as_float(c3.y) * di, a3);
    }
    for (; e < e1; ++e) {
        int2 c = cs[e];
        a0 = fmaf(bf2f(xw[(size_t)c.x * 64 + lane]), __int_as_float(c.y) * di, a0);
    }
    float acc = ((a0 + a1) + (a2 + a3)) + ((a4 + a5) + (a6 + a7));
    acc = fmaf(bf2f(xw[(size_t)wid * 64 + lane]), di * di, acc);
    if (BIAS_SILU) {
        acc += bias[lane];
        acc = acc / (1.0f + expf(-acc));
    }
    if (OUT_BF16) ((ushortT*)yv)[(size_t)wid * 64 + lane] = f2bf(acc);
    else          ((float*)yv)[(size_t)wid * 64 + lane] = acc;
}

extern "C" void kernel_launch(void* const* d_in, const int* in_sizes, int n_in,
                              void* d_out, int out_size, void* d_ws, size_t ws_size,
                              hipStream_t stream) {
    const float* noise_x = (const float*)d_in[0];
    const int*   edge    = (const int*)d_in[1];
    const int*   tptr    = (const int*)d_in[2];
    const int*   anm     = (const int*)d_in[3];
    const int*   nrm     = (const int*)d_in[4];
    const float* tw1     = (const float*)d_in[5];
    const float* tb1     = (const float*)d_in[6];
    const float* tw2     = (const float*)d_in[7];
    const float* tb2     = (const float*)d_in[8];
    const float* lemb    = (const float*)d_in[9];
    const float* w0      = (const float*)d_in[10];
    const float* b0      = (const float*)d_in[11];
    const float* w1      = (const float*)d_in[12];
    const float* b1      = (const float*)d_in[13];
    const float* w2      = (const float*)d_in[14];
    const float* b2      = (const float*)d_in[15];
    const float* w3      = (const float*)d_in[16];
    const float* b3      = (const float*)d_in[17];

    const int N = in_sizes[0] / 64;
    const int E = in_sizes[1] / 2;
    const int na = in_sizes[3];
    const int nn = in_sizes[4];
    float* out = (float*)d_out;

    // workspace carve-out (256B aligned)
    char* ws = (char*)d_ws;
    size_t o = 0;
    auto carve = [&](size_t bytes) -> char* {
        char* p = ws + o;
        o += (bytes + 255) & ~(size_t)255;
        return p;
    };
    int*     deg      = (int*)carve((size_t)N * 4);
    int*     flag     = (int*)carve((size_t)N * 4);
    int*     rowstart = (int*)carve((size_t)(N + 1) * 4);
    int*     writepos = (int*)carve((size_t)N * 4);
    int*     blocksum = (int*)carve(4096);
    int2*    cs       = (int2*)carve((size_t)E * 8);
    float*   dinv     = (float*)carve((size_t)N * 4);
    float*   temb     = (float*)carve(256);
    ushortT* wswz     = (ushortT*)carve(40960 * 2);
    ushortT* bufXT    = (ushortT*)carve((size_t)N * 64 * 2);  // x_t, reused as h1
    ushortT* aggX     = (ushortT*)carve((size_t)N * 64 * 2);  // agg0 out (bf16)
    ushortT* h0       = (ushortT*)carve((size_t)N * 128 * 2); // G0 out (bf16)
    ushortT* xw1      = (ushortT*)carve((size_t)N * 64 * 2);  // G1 out, reused as z3
    ushortT* aggH1    = (ushortT*)carve((size_t)N * 64 * 2);  // agg2 out (bf16)
    ushortT* h2       = (ushortT*)carve((size_t)N * 128 * 2); // G2 out (bf16)
    ushortT* h1       = bufXT;                                 // reuse
    ushortT* z3       = xw1;                                   // reuse

    const int nblkN = (N + 255) / 256;
    const int nblkE = (E + 255) / 256;
    const int nb = (N + 1023) / 1024;
    const int nmax = na > nn ? na : nn;
    const int aggBlk = (N + 3) / 4;          // 4 waves (nodes) per 256-thread block
    const int gblk = (N + 63) / 64;          // 64 rows per mfma-gemm block

    zero_kernel<<<nblkN, 256, 0, stream>>>(deg, flag, N);
    count_deg_kernel<<<nblkE, 256, 0, stream>>>(edge, deg, E);
    flags_kernel<<<(nmax + 255) / 256, 256, 0, stream>>>(anm, na, nrm, nn, flag);
    dinv_kernel<<<nblkN, 256, 0, stream>>>(deg, dinv, N);
    scan1_kernel<<<nb, 256, 0, stream>>>(deg, rowstart, blocksum, N);
    scan2_kernel<<<1, 64, 0, stream>>>(blocksum, nb);
    scan3_kernel<<<nblkN, 256, 0, stream>>>(rowstart, blocksum, writepos, N, E);
    fill_csr_kernel<<<nblkE, 256, 0, stream>>>(edge, writepos, cs, dinv, E);
    convw_kernel<<<160, 256, 0, stream>>>(w0, w1, w2, w3, wswz);
    temb_kernel<<<1, 64, 0, stream>>>(tptr, tw1, tb1, tw2, tb2, temb);
    xt_kernel<<<((size_t)N * 16 + 255) / 256, 256, 0, stream>>>(noise_x, temb, lemb, flag, bufXT, N);

    // conv0: aggX = agg(x_t) [bf16]; h0 = silu(aggX @ w0 + b0) [bf16]
    agg64_kernel<false, true><<<aggBlk, 256, 0, stream>>>(bufXT, rowstart, cs, dinv, nullptr, aggX, N);
    mfma_gemm_kernel<2, 8, true, true, false><<<gblk, 256, 0, stream>>>(aggX, nullptr, wswz, b0, h0, N);
    // conv1: xw1 = h0 @ w1 [bf16]; h1 = silu(agg(xw1) + b1) [bf16]
    mfma_gemm_kernel<4, 4, false, true, false><<<gblk, 256, 0, stream>>>(h0, nullptr, wswz + 8192, nullptr, xw1, N);
    agg64_kernel<true, true><<<aggBlk, 256, 0, stream>>>(xw1, rowstart, cs, dinv, b1, h1, N);
    // conv2: aggH1 = agg(h1) [bf16]; h2 = silu(aggH1 @ w2 + b2) [bf16]
    agg64_kernel<false, true><<<aggBlk, 256, 0, stream>>>(h1, rowstart, cs, dinv, nullptr, aggH1, N);
    mfma_gemm_kernel<2, 8, true, true, false><<<gblk, 256, 0, stream>>>(aggH1, nullptr, wswz + 16384, b2, h2, N);
    // conv3: z3 = h2 @ w3a + h0 @ w3b [bf16]; out = silu(agg(z3) + b3) [f32]
    mfma_gemm_kernel<8, 4, false, true, true><<<gblk, 256, 0, stream>>>(h2, h0, wswz + 24576, nullptr, z3, N);
    agg64_kernel<true, false><<<aggBlk, 256, 0, stream>>>(z3, rowstart, cs, dinv, b3, out, N);
}